// Round 17
// baseline (218.398 us; speedup 1.0000x reference)
//
#include <hip/hip_runtime.h>

#define NB  32
#define NC  256
#define NCQ 64
#define WHT 4096                  // 64*64 spatial
#define DQK ((size_t)NCQ * WHT)   // 262144
#define MV  ((size_t)NC * WHT)    // 1048576

typedef __attribute__((ext_vector_type(8))) short short8;
typedef __attribute__((ext_vector_type(4))) float f32x4;
typedef __attribute__((ext_vector_type(2))) float f32x2;
typedef unsigned short ushort_t;

__device__ __forceinline__ ushort_t bf16_rne(float f) {
    union { float f; unsigned u; } v; v.f = f;
    unsigned r = (v.u + 0x7fffu + ((v.u >> 16) & 1u)) >> 16;
    return (ushort_t)r;
}
__device__ __forceinline__ float bf16_f(ushort_t h) {
    union { unsigned u; float f; } v; v.u = ((unsigned)h) << 16; return v.f;
}

// fragment-order offset within one 64x256 W tile (elements):
// value W[r][kk] lands at (kb=kk>>5)*2048 + lh*512 + m*128 + ll*8 + e
__device__ __forceinline__ int frag_off(int r, int kk) {
    return ((kk >> 5) * 16 + ((kk >> 3) & 3) * 4 + (r >> 4)) * 128
           + (r & 15) * 8 + (kk & 7);
}

// ---------------------------------------------------------------------------
// P: convert weights to bf16 hi (+lo for q/k), permuted to MFMA fragment order
// ---------------------------------------------------------------------------
__global__ __launch_bounds__(256)
void prep_w(const float* __restrict__ Wq, const float* __restrict__ Wk,
            const float* __restrict__ Wv,
            ushort_t* __restrict__ wv_hi,
            ushort_t* __restrict__ wq_hi, ushort_t* __restrict__ wq_lo,
            ushort_t* __restrict__ wk_hi, ushort_t* __restrict__ wk_lo)
{
    int i = blockIdx.x * 256 + threadIdx.x;
    if (i < 65536) {                       // Wv: 256 rows -> 4 tiles of 64
        int R = i >> 8, kk = i & 255;
        wv_hi[(R >> 6) * 16384 + frag_off(R & 63, kk)] = bf16_rne(Wv[i]);
    } else if (i < 81920) {                // Wq: 64 rows
        int j = i - 65536; int r = j >> 8, kk = j & 255;
        float f = Wq[j]; ushort_t h = bf16_rne(f);
        int o = frag_off(r, kk);
        wq_hi[o] = h; wq_lo[o] = bf16_rne(f - bf16_f(h));
    } else if (i < 98304) {                // Wk: 64 rows
        int j = i - 81920; int r = j >> 8, kk = j & 255;
        float f = Wk[j]; ushort_t h = bf16_rne(f);
        int o = frag_off(r, kk);
        wk_hi[o] = h; wk_lo[o] = bf16_rne(f - bf16_f(h));
    }
}

// load one kb-chunk's B tile (2 n-groups x 8 k-elems) into register buffer
#define LOADB(dst, kbv) do {                                            \
    const float* xk_ = xw + (size_t)(kbv) * 32 * WHT;                   \
    _Pragma("unroll") for (int n_ = 0; n_ < 2; ++n_)                    \
    _Pragma("unroll") for (int e_ = 0; e_ < 8; ++e_)                    \
        dst[n_][e_] = xk_[(size_t)e_ * WHT + n_ * 16];                  \
} while (0)

// ---------------------------------------------------------------------------
// K1: fused q/k/v projections via bf16 MFMA. R5/R13/R15 structure; ONE new
// element: per-iteration sched_group_barrier directives (T19) pinning the
// machine-scheduler order to [next-tile VMEM loads][W ds_reads][MFMAs] so
// the compiler cannot sink each x-load to its consumer (the R5-R16 failure
// mode: per-step serialized L2 round-trips, VGPR=60 proof).
// Block = 512 threads = 8 waves; per-wave tile 64x32. q/k: 3-pass hi/lo
// split; v: hi-only, stored bf16.
// ---------------------------------------------------------------------------
__global__ __launch_bounds__(512, 4)
void qkv_mfma(const float* __restrict__ x0, const float* __restrict__ x1,
              const ushort_t* __restrict__ wv_hi,
              const ushort_t* __restrict__ wq_hi, const ushort_t* __restrict__ wq_lo,
              const ushort_t* __restrict__ wk_hi, const ushort_t* __restrict__ wk_lo,
              const float* __restrict__ bq, const float* __restrict__ bk,
              const float* __restrict__ bv,
              float* __restrict__ q, float* __restrict__ k,
              ushort_t* __restrict__ vbf)
{
    __shared__ ushort_t lds_hi[16384];   // 32 KB, fragment order
    __shared__ ushort_t lds_lo[16384];   // 32 KB (qk blocks only)

    const int t   = threadIdx.x;
    const int bid = blockIdx.x;
    // bid -> (b, nt, mt): all 6 mt of one (b,nt) panel on one XCD (bid%8)
    const int xcd = bid & 7;
    const int sl  = bid >> 3;            // 0..383
    const int mt  = sl % 6;
    const int g   = (sl / 6) * 8 + xcd;  // 0..511
    const int nt  = g & 15;
    const int b   = g >> 4;

    const bool isV = (mt < 4);
    const bool isQ = (mt == 4);

    const int wave = t >> 6;
    const int lane = t & 63;
    const int lh   = lane >> 4;          // k-subchunk selector (0..3)
    const int ll   = lane & 15;

    const ushort_t* whi = isV ? (wv_hi + mt * 16384) : (isQ ? wq_hi : wk_hi);
    const ushort_t* wlo = isQ ? wq_lo : wk_lo;

    // ---- stage W tile(s) to LDS (linear fragment-order copy) ----
#pragma unroll
    for (int r = 0; r < 4; ++r)
        *(short8*)&lds_hi[(r * 512 + t) * 8] = *(const short8*)(whi + (r * 512 + t) * 8);
    if (!isV) {
#pragma unroll
        for (int r = 0; r < 4; ++r)
            *(short8*)&lds_lo[(r * 512 + t) * 8] = *(const short8*)(wlo + (r * 512 + t) * 8);
    }
    __syncthreads();

    const float* xw = ((mt == 5) ? x1 : x0) + (size_t)b * NC * WHT
                      + nt * 256 + wave * 32 + ll + (size_t)lh * 8 * WHT;
    const int abase = lh * 512 + ll * 8;

    f32x4 acc[4][2];
#pragma unroll
    for (int m = 0; m < 4; ++m)
#pragma unroll
        for (int n = 0; n < 2; ++n) acc[m][n] = (f32x4){0.f, 0.f, 0.f, 0.f};

    float xfA[2][8], xfB[2][8];
    LOADB(xfA, 0);

#pragma unroll
    for (int kb = 0; kb < 8; ++kb) {
        float (*cur)[8] = (kb & 1) ? xfB : xfA;
        float (*nxt)[8] = (kb & 1) ? xfA : xfB;
        if (kb < 7) LOADB(nxt, kb + 1);

        // ---- hi = top16 truncation, packed via v_perm ----
        short8 bh[2];
#pragma unroll
        for (int n = 0; n < 2; ++n) {
            union { unsigned u[4]; short8 s; } pk;
#pragma unroll
            for (int p = 0; p < 4; ++p)
                pk.u[p] = __builtin_amdgcn_perm(
                    __float_as_uint(cur[n][2 * p + 1]),
                    __float_as_uint(cur[n][2 * p]), 0x07060302u);
            bh[n] = pk.s;
        }

        if (isV) {
#pragma unroll
            for (int m = 0; m < 4; ++m) {
                short8 a_hi = *(const short8*)&lds_hi[kb * 2048 + abase + m * 128];
#pragma unroll
                for (int n = 0; n < 2; ++n)
                    acc[m][n] = __builtin_amdgcn_mfma_f32_16x16x32_bf16(
                        a_hi, bh[n], acc[m][n], 0, 0, 0);
            }
            // T19: pin scheduler order for this iteration:
            // [16 next-tile global loads][8 W ds_reads][8 MFMAs]
            if (kb < 7)
                __builtin_amdgcn_sched_group_barrier(0x020, 16, 0); // VMEM_READ
            __builtin_amdgcn_sched_group_barrier(0x100, 8, 0);      // DS_READ
            __builtin_amdgcn_sched_group_barrier(0x008, 8, 0);      // MFMA
        } else {
            short8 bl[2];
#pragma unroll
            for (int n = 0; n < 2; ++n) {
                float lo[8];
#pragma unroll
                for (int e = 0; e < 8; ++e) {
                    float hf = __uint_as_float(__float_as_uint(cur[n][e]) & 0xffff0000u);
                    lo[e] = cur[n][e] - hf;
                }
                union { unsigned u[4]; short8 s; } pk;
#pragma unroll
                for (int p = 0; p < 4; ++p)
                    pk.u[p] = __builtin_amdgcn_perm(
                        __float_as_uint(lo[2 * p + 1]),
                        __float_as_uint(lo[2 * p]), 0x07060302u);
                bl[n] = pk.s;
            }
#pragma unroll
            for (int m = 0; m < 4; ++m) {
                short8 a_hi = *(const short8*)&lds_hi[kb * 2048 + abase + m * 128];
                short8 a_lo = *(const short8*)&lds_lo[kb * 2048 + abase + m * 128];
#pragma unroll
                for (int n = 0; n < 2; ++n) {
                    acc[m][n] = __builtin_amdgcn_mfma_f32_16x16x32_bf16(
                        a_hi, bh[n], acc[m][n], 0, 0, 0);
                    acc[m][n] = __builtin_amdgcn_mfma_f32_16x16x32_bf16(
                        a_hi, bl[n], acc[m][n], 0, 0, 0);
                    acc[m][n] = __builtin_amdgcn_mfma_f32_16x16x32_bf16(
                        a_lo, bh[n], acc[m][n], 0, 0, 0);
                }
            }
            if (kb < 7)
                __builtin_amdgcn_sched_group_barrier(0x020, 16, 0); // VMEM_READ
            __builtin_amdgcn_sched_group_barrier(0x100, 16, 0);     // DS_READ
            __builtin_amdgcn_sched_group_barrier(0x008, 24, 0);     // MFMA
        }
    }

    // ---- epilogue ----
    const int colbase = nt * 256 + wave * 32;
    if (isV) {
        ushort_t* outp = vbf + ((size_t)b * NC + mt * 64) * WHT + colbase;
        const float* bias = bv + mt * 64;
#pragma unroll
        for (int m = 0; m < 4; ++m)
#pragma unroll
            for (int n = 0; n < 2; ++n)
#pragma unroll
                for (int r = 0; r < 4; ++r) {
                    const int row = m * 16 + 4 * lh + r;
                    outp[(size_t)row * WHT + n * 16 + ll] =
                        bf16_rne(acc[m][n][r] + bias[row]);
                }
    } else {
        float* outp = (isQ ? q : k) + (size_t)b * NCQ * WHT + colbase;
        const float* bias = isQ ? bq : bk;
#pragma unroll
        for (int m = 0; m < 4; ++m)
#pragma unroll
            for (int n = 0; n < 2; ++n)
#pragma unroll
                for (int r = 0; r < 4; ++r) {
                    const int row = m * 16 + 4 * lh + r;
                    outp[(size_t)row * WHT + n * 16 + ll] =
                        acc[m][n][r] + bias[row];
                }
    }
}

// ---------------------------------------------------------------------------
// K2: energy[i,j] = sum_d k[i,d]*q[j,d]  (32x32, K=262144).
// 512 blocks x 512-d range (4 chunks of 128 staged in LDS via float4;
// accumulators carried in registers) -> q,k read ONCE; atomics 512/address.
// ---------------------------------------------------------------------------
__global__ __launch_bounds__(512)
void energy_kernel(const float* __restrict__ q, const float* __restrict__ k,
                   float* __restrict__ energy)
{
    __shared__ float kt[32][132];
    __shared__ float qt[32][132];

    const int t   = threadIdx.x;
    const int d00 = blockIdx.x * 512;
    const int i   = t >> 4;
    const int j   = t & 15;

    float a0 = 0.f, a1 = 0.f, a2 = 0.f, a3 = 0.f;
    float b0 = 0.f, b1 = 0.f, b2 = 0.f, b3 = 0.f;

    for (int c = 0; c < 4; ++c) {
        const int d0 = d00 + c * 128;
        __syncthreads();
#pragma unroll
        for (int u = 0; u < 2; ++u) {
            int idx = (u * 512 + t) * 4;
            int ii = idx >> 7, d = idx & 127;
            *(f32x4*)&kt[ii][d] = *(const f32x4*)&k[(size_t)ii * DQK + d0 + d];
            *(f32x4*)&qt[ii][d] = *(const f32x4*)&q[(size_t)ii * DQK + d0 + d];
        }
        __syncthreads();

#pragma unroll 4
        for (int d = 0; d < 128; d += 4) {
            float k0 = kt[i][d], k1 = kt[i][d + 1], k2 = kt[i][d + 2], k3 = kt[i][d + 3];
            a0 = fmaf(k0, qt[j][d],      a0);
            a1 = fmaf(k1, qt[j][d + 1],  a1);
            a2 = fmaf(k2, qt[j][d + 2],  a2);
            a3 = fmaf(k3, qt[j][d + 3],  a3);
            b0 = fmaf(k0, qt[j + 16][d],     b0);
            b1 = fmaf(k1, qt[j + 16][d + 1], b1);
            b2 = fmaf(k2, qt[j + 16][d + 2], b2);
            b3 = fmaf(k3, qt[j + 16][d + 3], b3);
        }
    }

    atomicAdd(&energy[i * 32 + j],      (a0 + a1) + (a2 + a3));
    atomicAdd(&energy[i * 32 + j + 16], (b0 + b1) + (b2 + b3));
}

// ---------------------------------------------------------------------------
// K3: softmax (per-block recompute, 32x32) + out = gamma*(A@v) + x1.
// Block 0 also writes the attention output. v is bf16-packed. Streaming
// arrays use nontemporal loads/stores.
// ---------------------------------------------------------------------------
__global__ __launch_bounds__(256)
void out_kernel(const ushort_t* __restrict__ vbf, const float* __restrict__ energy,
                const float* __restrict__ x1, const float* __restrict__ gamma,
                float* __restrict__ out, float* __restrict__ att_out)
{
    __shared__ float att_s[1024];
    const int t = threadIdx.x;

    if (t < 32) {
        float e[32];
        float m = -1e30f;
#pragma unroll
        for (int j = 0; j < 32; ++j) { e[j] = energy[t * 32 + j]; m = fmaxf(m, e[j]); }
        float s = 0.f;
#pragma unroll
        for (int j = 0; j < 32; ++j) { e[j] = __expf(e[j] - m); s += e[j]; }
        float inv = 1.f / s;
#pragma unroll
        for (int j = 0; j < 32; ++j) att_s[t * 32 + j] = e[j] * inv;
    }
    __syncthreads();

    if (blockIdx.x == 0) {
        for (int r = t; r < 1024; r += 256) att_out[r] = att_s[r];
    }

    const size_t m0 = (size_t)blockIdx.x * 512 + 2 * t;

    float v0[32], v1[32];
#pragma unroll
    for (int j = 0; j < 32; ++j) {
        unsigned u = __builtin_nontemporal_load(
            (const unsigned*)(vbf + (size_t)j * MV + m0));
        v0[j] = __uint_as_float(u << 16);
        v1[j] = __uint_as_float(u & 0xffff0000u);
    }

    const float g = gamma[0];
    for (int i = 0; i < 32; ++i) {
        float a0 = 0.f, a1 = 0.f;
#pragma unroll
        for (int j = 0; j < 32; ++j) {
            float w = att_s[i * 32 + j];
            a0 = fmaf(w, v0[j], a0);
            a1 = fmaf(w, v1[j], a1);
        }
        f32x2 xx = __builtin_nontemporal_load(
            (const f32x2*)(x1 + (size_t)i * MV + m0));
        f32x2 oo; oo.x = g * a0 + xx.x; oo.y = g * a1 + xx.y;
        __builtin_nontemporal_store(oo, (f32x2*)(out + (size_t)i * MV + m0));
    }
}

// ---------------------------------------------------------------------------
extern "C" void kernel_launch(void* const* d_in, const int* in_sizes, int n_in,
                              void* d_out, int out_size, void* d_ws, size_t ws_size,
                              hipStream_t stream)
{
    const float* x0    = (const float*)d_in[0];
    const float* x1    = (const float*)d_in[1];
    const float* Wq    = (const float*)d_in[2];
    const float* bq    = (const float*)d_in[3];
    const float* Wk    = (const float*)d_in[4];
    const float* bk    = (const float*)d_in[5];
    const float* Wv    = (const float*)d_in[6];
    const float* bv    = (const float*)d_in[7];
    const float* gamma = (const float*)d_in[8];

    float* ws     = (float*)d_ws;
    float* q      = ws;                                  // 8,388,608 f
    float* k      = q + (size_t)NB * NCQ * WHT;          // 8,388,608 f
    float* energy = k + (size_t)NB * NCQ * WHT;          //     1,024 f

    ushort_t* wv_hi = (ushort_t*)(energy + 1024);        // 65,536 us (16B-aligned)
    ushort_t* wq_hi = wv_hi + 65536;
    ushort_t* wq_lo = wq_hi + 16384;
    ushort_t* wk_hi = wq_lo + 16384;
    ushort_t* wk_lo = wk_hi + 16384;
    ushort_t* vbf   = wk_lo + 16384;                     // 33,554,432 us

    float* out     = (float*)d_out;
    float* att_out = out + (size_t)NB * NC * WHT;

    hipMemsetAsync(energy, 0, 1024 * sizeof(float), stream);

    prep_w<<<384, 256, 0, stream>>>(Wq, Wk, Wv, wv_hi, wq_hi, wq_lo, wk_hi, wk_lo);
    qkv_mfma<<<3072, 512, 0, stream>>>(x0, x1, wv_hi, wq_hi, wq_lo, wk_hi, wk_lo,
                                       bq, bk, bv, q, k, vbf);
    energy_kernel<<<512, 512, 0, stream>>>(q, k, energy);
    out_kernel<<<2048, 256, 0, stream>>>(vbf, energy, x1, gamma, out, att_out);
}

// Round 18
// 204.930 us; speedup vs baseline: 1.0657x; 1.0657x over previous
//
#include <hip/hip_runtime.h>

#define NB  32
#define NC  256
#define NCQ 64
#define WHT 4096                  // 64*64 spatial
#define DQK ((size_t)NCQ * WHT)   // 262144
#define MV  ((size_t)NC * WHT)    // 1048576

typedef __attribute__((ext_vector_type(8))) short short8;
typedef __attribute__((ext_vector_type(4))) float f32x4;
typedef __attribute__((ext_vector_type(2))) float f32x2;
typedef unsigned short ushort_t;

__device__ __forceinline__ ushort_t bf16_rne(float f) {
    union { float f; unsigned u; } v; v.f = f;
    unsigned r = (v.u + 0x7fffu + ((v.u >> 16) & 1u)) >> 16;
    return (ushort_t)r;
}
__device__ __forceinline__ float bf16_f(ushort_t h) {
    union { unsigned u; float f; } v; v.u = ((unsigned)h) << 16; return v.f;
}

// fragment-order offset within one 64x256 W tile (elements):
// value W[r][kk] lands at (kb=kk>>5)*2048 + lh*512 + m*128 + ll*8 + e
__device__ __forceinline__ int frag_off(int r, int kk) {
    return ((kk >> 5) * 16 + ((kk >> 3) & 3) * 4 + (r >> 4)) * 128
           + (r & 15) * 8 + (kk & 7);
}

// ---------------------------------------------------------------------------
// P: convert weights to bf16 hi (+lo for q/k), permuted to MFMA fragment order
// ---------------------------------------------------------------------------
__global__ __launch_bounds__(256)
void prep_w(const float* __restrict__ Wq, const float* __restrict__ Wk,
            const float* __restrict__ Wv,
            ushort_t* __restrict__ wv_hi,
            ushort_t* __restrict__ wq_hi, ushort_t* __restrict__ wq_lo,
            ushort_t* __restrict__ wk_hi, ushort_t* __restrict__ wk_lo)
{
    int i = blockIdx.x * 256 + threadIdx.x;
    if (i < 65536) {                       // Wv: 256 rows -> 4 tiles of 64
        int R = i >> 8, kk = i & 255;
        wv_hi[(R >> 6) * 16384 + frag_off(R & 63, kk)] = bf16_rne(Wv[i]);
    } else if (i < 81920) {                // Wq: 64 rows
        int j = i - 65536; int r = j >> 8, kk = j & 255;
        float f = Wq[j]; ushort_t h = bf16_rne(f);
        int o = frag_off(r, kk);
        wq_hi[o] = h; wq_lo[o] = bf16_rne(f - bf16_f(h));
    } else if (i < 98304) {                // Wk: 64 rows
        int j = i - 81920; int r = j >> 8, kk = j & 255;
        float f = Wk[j]; ushort_t h = bf16_rne(f);
        int o = frag_off(r, kk);
        wk_hi[o] = h; wk_lo[o] = bf16_rne(f - bf16_f(h));
    }
}

// load one kb-chunk's B tile (2 n-groups x 8 k-elems) into register buffer
#define LOADB(dst, kbv) do {                                            \
    const float* xk_ = xw + (size_t)(kbv) * 32 * WHT;                   \
    _Pragma("unroll") for (int n_ = 0; n_ < 2; ++n_)                    \
    _Pragma("unroll") for (int e_ = 0; e_ < 8; ++e_)                    \
        dst[n_][e_] = xk_[(size_t)e_ * WHT + n_ * 16];                  \
} while (0)

// ---------------------------------------------------------------------------
// K1: fused q/k/v projections via bf16 MFMA. R5/R13/R15 structure VERBATIM —
// the measured optimum of this family (122-127 us, absmax 0.03125) across
// 13 structural/schedule variants (R6-R17 all at-or-worse; see session log).
// Block = 512 threads = 8 waves; block tile 64 rows x 256 spatial; per-wave
// tile 64x32. W fragments staged to LDS once per block (one barrier,
// conflict-free b128 reads). B (x) loads register-double-buffered across the
// unrolled kb loop. q/k: 3-pass hi/lo split; v: hi-only, stored bf16.
// ---------------------------------------------------------------------------
__global__ __launch_bounds__(512, 4)
void qkv_mfma(const float* __restrict__ x0, const float* __restrict__ x1,
              const ushort_t* __restrict__ wv_hi,
              const ushort_t* __restrict__ wq_hi, const ushort_t* __restrict__ wq_lo,
              const ushort_t* __restrict__ wk_hi, const ushort_t* __restrict__ wk_lo,
              const float* __restrict__ bq, const float* __restrict__ bk,
              const float* __restrict__ bv,
              float* __restrict__ q, float* __restrict__ k,
              ushort_t* __restrict__ vbf)
{
    __shared__ ushort_t lds_hi[16384];   // 32 KB, fragment order
    __shared__ ushort_t lds_lo[16384];   // 32 KB (qk blocks only)

    const int t   = threadIdx.x;
    const int bid = blockIdx.x;
    // bid -> (b, nt, mt): all 6 mt of one (b,nt) panel on one XCD (bid%8)
    const int xcd = bid & 7;
    const int sl  = bid >> 3;            // 0..383
    const int mt  = sl % 6;
    const int g   = (sl / 6) * 8 + xcd;  // 0..511
    const int nt  = g & 15;
    const int b   = g >> 4;

    const bool isV = (mt < 4);
    const bool isQ = (mt == 4);

    const int wave = t >> 6;
    const int lane = t & 63;
    const int lh   = lane >> 4;          // k-subchunk selector (0..3)
    const int ll   = lane & 15;

    const ushort_t* whi = isV ? (wv_hi + mt * 16384) : (isQ ? wq_hi : wk_hi);
    const ushort_t* wlo = isQ ? wq_lo : wk_lo;

    // ---- stage W tile(s) to LDS (linear fragment-order copy) ----
#pragma unroll
    for (int r = 0; r < 4; ++r)
        *(short8*)&lds_hi[(r * 512 + t) * 8] = *(const short8*)(whi + (r * 512 + t) * 8);
    if (!isV) {
#pragma unroll
        for (int r = 0; r < 4; ++r)
            *(short8*)&lds_lo[(r * 512 + t) * 8] = *(const short8*)(wlo + (r * 512 + t) * 8);
    }
    __syncthreads();

    const float* xw = ((mt == 5) ? x1 : x0) + (size_t)b * NC * WHT
                      + nt * 256 + wave * 32 + ll + (size_t)lh * 8 * WHT;
    const int abase = lh * 512 + ll * 8;

    f32x4 acc[4][2];
#pragma unroll
    for (int m = 0; m < 4; ++m)
#pragma unroll
        for (int n = 0; n < 2; ++n) acc[m][n] = (f32x4){0.f, 0.f, 0.f, 0.f};

    float xfA[2][8], xfB[2][8];
    LOADB(xfA, 0);

#pragma unroll
    for (int kb = 0; kb < 8; ++kb) {
        float (*cur)[8] = (kb & 1) ? xfB : xfA;
        float (*nxt)[8] = (kb & 1) ? xfA : xfB;
        if (kb < 7) LOADB(nxt, kb + 1);

        // ---- hi = top16 truncation, packed via v_perm ----
        short8 bh[2];
#pragma unroll
        for (int n = 0; n < 2; ++n) {
            union { unsigned u[4]; short8 s; } pk;
#pragma unroll
            for (int p = 0; p < 4; ++p)
                pk.u[p] = __builtin_amdgcn_perm(
                    __float_as_uint(cur[n][2 * p + 1]),
                    __float_as_uint(cur[n][2 * p]), 0x07060302u);
            bh[n] = pk.s;
        }

        if (isV) {
#pragma unroll
            for (int m = 0; m < 4; ++m) {
                short8 a_hi = *(const short8*)&lds_hi[kb * 2048 + abase + m * 128];
#pragma unroll
                for (int n = 0; n < 2; ++n)
                    acc[m][n] = __builtin_amdgcn_mfma_f32_16x16x32_bf16(
                        a_hi, bh[n], acc[m][n], 0, 0, 0);
            }
        } else {
            short8 bl[2];
#pragma unroll
            for (int n = 0; n < 2; ++n) {
                float lo[8];
#pragma unroll
                for (int e = 0; e < 8; ++e) {
                    float hf = __uint_as_float(__float_as_uint(cur[n][e]) & 0xffff0000u);
                    lo[e] = cur[n][e] - hf;
                }
                union { unsigned u[4]; short8 s; } pk;
#pragma unroll
                for (int p = 0; p < 4; ++p)
                    pk.u[p] = __builtin_amdgcn_perm(
                        __float_as_uint(lo[2 * p + 1]),
                        __float_as_uint(lo[2 * p]), 0x07060302u);
                bl[n] = pk.s;
            }
#pragma unroll
            for (int m = 0; m < 4; ++m) {
                short8 a_hi = *(const short8*)&lds_hi[kb * 2048 + abase + m * 128];
                short8 a_lo = *(const short8*)&lds_lo[kb * 2048 + abase + m * 128];
#pragma unroll
                for (int n = 0; n < 2; ++n) {
                    acc[m][n] = __builtin_amdgcn_mfma_f32_16x16x32_bf16(
                        a_hi, bh[n], acc[m][n], 0, 0, 0);
                    acc[m][n] = __builtin_amdgcn_mfma_f32_16x16x32_bf16(
                        a_hi, bl[n], acc[m][n], 0, 0, 0);
                    acc[m][n] = __builtin_amdgcn_mfma_f32_16x16x32_bf16(
                        a_lo, bh[n], acc[m][n], 0, 0, 0);
                }
            }
        }
    }

    // ---- epilogue ----
    const int colbase = nt * 256 + wave * 32;
    if (isV) {
        ushort_t* outp = vbf + ((size_t)b * NC + mt * 64) * WHT + colbase;
        const float* bias = bv + mt * 64;
#pragma unroll
        for (int m = 0; m < 4; ++m)
#pragma unroll
            for (int n = 0; n < 2; ++n)
#pragma unroll
                for (int r = 0; r < 4; ++r) {
                    const int row = m * 16 + 4 * lh + r;
                    outp[(size_t)row * WHT + n * 16 + ll] =
                        bf16_rne(acc[m][n][r] + bias[row]);
                }
    } else {
        float* outp = (isQ ? q : k) + (size_t)b * NCQ * WHT + colbase;
        const float* bias = isQ ? bq : bk;
#pragma unroll
        for (int m = 0; m < 4; ++m)
#pragma unroll
            for (int n = 0; n < 2; ++n)
#pragma unroll
                for (int r = 0; r < 4; ++r) {
                    const int row = m * 16 + 4 * lh + r;
                    outp[(size_t)row * WHT + n * 16 + ll] =
                        acc[m][n][r] + bias[row];
                }
    }
}

// ---------------------------------------------------------------------------
// K2: energy[i,j] = sum_d k[i,d]*q[j,d]  (32x32, K=262144).
// 512 blocks x 512-d range (4 chunks of 128 staged in LDS via float4;
// accumulators carried in registers) -> q,k read ONCE; atomics 512/address.
// Rows padded to 132 (16B-aligned b128 stores; 2-way-free bank pattern).
// ---------------------------------------------------------------------------
__global__ __launch_bounds__(512)
void energy_kernel(const float* __restrict__ q, const float* __restrict__ k,
                   float* __restrict__ energy)
{
    __shared__ float kt[32][132];
    __shared__ float qt[32][132];

    const int t   = threadIdx.x;
    const int d00 = blockIdx.x * 512;
    const int i   = t >> 4;
    const int j   = t & 15;

    float a0 = 0.f, a1 = 0.f, a2 = 0.f, a3 = 0.f;
    float b0 = 0.f, b1 = 0.f, b2 = 0.f, b3 = 0.f;

    for (int c = 0; c < 4; ++c) {
        const int d0 = d00 + c * 128;
        __syncthreads();                 // protect LDS reuse from prev chunk
#pragma unroll
        for (int u = 0; u < 2; ++u) {
            int idx = (u * 512 + t) * 4; // 0..4095, float4 granules
            int ii = idx >> 7, d = idx & 127;
            *(f32x4*)&kt[ii][d] = *(const f32x4*)&k[(size_t)ii * DQK + d0 + d];
            *(f32x4*)&qt[ii][d] = *(const f32x4*)&q[(size_t)ii * DQK + d0 + d];
        }
        __syncthreads();

#pragma unroll 4
        for (int d = 0; d < 128; d += 4) {
            float k0 = kt[i][d], k1 = kt[i][d + 1], k2 = kt[i][d + 2], k3 = kt[i][d + 3];
            a0 = fmaf(k0, qt[j][d],      a0);
            a1 = fmaf(k1, qt[j][d + 1],  a1);
            a2 = fmaf(k2, qt[j][d + 2],  a2);
            a3 = fmaf(k3, qt[j][d + 3],  a3);
            b0 = fmaf(k0, qt[j + 16][d],     b0);
            b1 = fmaf(k1, qt[j + 16][d + 1], b1);
            b2 = fmaf(k2, qt[j + 16][d + 2], b2);
            b3 = fmaf(k3, qt[j + 16][d + 3], b3);
        }
    }

    atomicAdd(&energy[i * 32 + j],      (a0 + a1) + (a2 + a3));
    atomicAdd(&energy[i * 32 + j + 16], (b0 + b1) + (b2 + b3));
}

// ---------------------------------------------------------------------------
// K3: softmax (per-block recompute, 32x32) + out = gamma*(A@v) + x1.
// Block 0 also writes the attention output. v is bf16-packed. Streaming
// arrays (vbf, x1, out) use nontemporal loads/stores -- zero reuse, skip L2.
// ---------------------------------------------------------------------------
__global__ __launch_bounds__(256)
void out_kernel(const ushort_t* __restrict__ vbf, const float* __restrict__ energy,
                const float* __restrict__ x1, const float* __restrict__ gamma,
                float* __restrict__ out, float* __restrict__ att_out)
{
    __shared__ float att_s[1024];
    const int t = threadIdx.x;

    if (t < 32) {
        float e[32];
        float m = -1e30f;
#pragma unroll
        for (int j = 0; j < 32; ++j) { e[j] = energy[t * 32 + j]; m = fmaxf(m, e[j]); }
        float s = 0.f;
#pragma unroll
        for (int j = 0; j < 32; ++j) { e[j] = __expf(e[j] - m); s += e[j]; }
        float inv = 1.f / s;
#pragma unroll
        for (int j = 0; j < 32; ++j) att_s[t * 32 + j] = e[j] * inv;
    }
    __syncthreads();

    if (blockIdx.x == 0) {
        for (int r = t; r < 1024; r += 256) att_out[r] = att_s[r];
    }

    const size_t m0 = (size_t)blockIdx.x * 512 + 2 * t;

    float v0[32], v1[32];
#pragma unroll
    for (int j = 0; j < 32; ++j) {
        unsigned u = __builtin_nontemporal_load(
            (const unsigned*)(vbf + (size_t)j * MV + m0));
        v0[j] = __uint_as_float(u << 16);
        v1[j] = __uint_as_float(u & 0xffff0000u);
    }

    const float g = gamma[0];
    for (int i = 0; i < 32; ++i) {
        float a0 = 0.f, a1 = 0.f;
#pragma unroll
        for (int j = 0; j < 32; ++j) {
            float w = att_s[i * 32 + j];
            a0 = fmaf(w, v0[j], a0);
            a1 = fmaf(w, v1[j], a1);
        }
        f32x2 xx = __builtin_nontemporal_load(
            (const f32x2*)(x1 + (size_t)i * MV + m0));
        f32x2 oo; oo.x = g * a0 + xx.x; oo.y = g * a1 + xx.y;
        __builtin_nontemporal_store(oo, (f32x2*)(out + (size_t)i * MV + m0));
    }
}

// ---------------------------------------------------------------------------
extern "C" void kernel_launch(void* const* d_in, const int* in_sizes, int n_in,
                              void* d_out, int out_size, void* d_ws, size_t ws_size,
                              hipStream_t stream)
{
    const float* x0    = (const float*)d_in[0];
    const float* x1    = (const float*)d_in[1];
    const float* Wq    = (const float*)d_in[2];
    const float* bq    = (const float*)d_in[3];
    const float* Wk    = (const float*)d_in[4];
    const float* bk    = (const float*)d_in[5];
    const float* Wv    = (const float*)d_in[6];
    const float* bv    = (const float*)d_in[7];
    const float* gamma = (const float*)d_in[8];

    float* ws     = (float*)d_ws;
    float* q      = ws;                                  // 8,388,608 f
    float* k      = q + (size_t)NB * NCQ * WHT;          // 8,388,608 f
    float* energy = k + (size_t)NB * NCQ * WHT;          //     1,024 f

    ushort_t* wv_hi = (ushort_t*)(energy + 1024);        // 65,536 us (16B-aligned)
    ushort_t* wq_hi = wv_hi + 65536;
    ushort_t* wq_lo = wq_hi + 16384;
    ushort_t* wk_hi = wq_lo + 16384;
    ushort_t* wk_lo = wk_hi + 16384;
    ushort_t* vbf   = wk_lo + 16384;                     // 33,554,432 us

    float* out     = (float*)d_out;
    float* att_out = out + (size_t)NB * NC * WHT;

    hipMemsetAsync(energy, 0, 1024 * sizeof(float), stream);

    prep_w<<<384, 256, 0, stream>>>(Wq, Wk, Wv, wv_hi, wq_hi, wq_lo, wk_hi, wk_lo);
    qkv_mfma<<<3072, 512, 0, stream>>>(x0, x1, wv_hi, wq_hi, wq_lo, wk_hi, wk_lo,
                                       bq, bk, bv, q, k, vbf);
    energy_kernel<<<512, 512, 0, stream>>>(q, k, energy);
    out_kernel<<<2048, 256, 0, stream>>>(vbf, energy, x1, gamma, out, att_out);
}